// Round 8
// baseline (1035.131 us; speedup 1.0000x reference)
//
#include <hip/hip_runtime.h>
#include <math.h>

// DepthToVoxelConverter: B=32, (B,4,512,512) fp32 -> (B,4,64^3) fp32
// out ch0 = occupancy, ch1..3 = mean rgb per voxel.
//
// History:
//  R1-R8: scatter-atomics -> bucket+LDS-reduce evolution, 430->242us.
//  R9: entry repack (ix in u64, Q14), hot-first reduce, nt ld/st: 242.2.
//  R10: entries 491->120MB: NULL -> ws poison is a FIXED 512MiB tax.
//      Fixed harness tax ~150-158us/iter total.
//  R11: quad-segregated fine buckets (b,ix,iyq): NULL (242.7).
//  R12: rgb GATHER in reduce: 303.5 REGRESSION (reduce=121us measured,
//      latency-bound cross-XCD gather). Colors stream through append.
//  R13: 512thr append, depth-only across barriers: 244.8 (null).
//  R14: MEASUREMENT: doubled append in-dispatch: total +31.2us and the
//      2x dispatch still < 83us => single append ~31-35us (floor ~24),
//      reduce ~30 (floor ~26, R12 calibration). Remaining named slack:
//      launch boundaries + reduce dispatch ramp + straggler tails.
//  R15: FUSED PERSISTENT kernel: one 1024-block x 256-thr launch does
//      init-consume, 4 append rounds, then 8 reduce rounds; per-batch
//      done[32] flags (device-scope release/acquire) let reduce start
//      while append stragglers finish. Co-residency guaranteed:
//      launch_bounds(256,4) => >=4 blocks/CU (VGPR<=128), LDS 19.4KB
//      => 8/CU; 1024 = 4/CU x 256CU all resident => spin cannot
//      deadlock. Reduce bucket assignment rotates ix-heat per batch
//      (+37*k mod 256) to keep persistent-block load balanced.
//
// Entry u64 layout (both LDS staging and global):
//   [62:57]=ix [56:51]=iy [50:45]=iz [44:30]=r14 [29:15]=g14 [14:0]=b14
//   fine bin  = bits [62:55] = (ix<<2)|(iy>>4)

constexpr int V = 64;
constexpr int V3 = V * V * V;           // 262144 = 2^18
constexpr int Wd = 512, Hd = 512;
constexpr int NPIX = Wd * Hd;           // 262144 = 2^18
constexpr int NBUCKET = 32 * 256;       // (b, ix, iyq) fine buckets = 8192
constexpr unsigned CAPQ = 3456;         // entries per fine bucket (even)
constexpr float CQ = 16384.0f;          // color quant Q14
constexpr int PPB = 2048;               // pixels per append block
constexpr int CHUNKS = NPIX / PPB;      // 128 chunks per batch
constexpr int GRID = 1024;              // persistent blocks (4/CU, resident)

// clang-native 4-float vector: required by __builtin_nontemporal_{load,store}
typedef float f4 __attribute__((ext_vector_type(4)));

__device__ __forceinline__ bool unproject(int w, int h, float d,
                                          int& ix, int& iy, int& iz) {
    // depth_valid = (d > 0) & (d < 10) & isfinite(d)
    if (!(d > 0.0f) || !(d < 10.0f) || !isfinite(d)) return false;
    const float fx = 256.0f, cx = 256.0f, cy = 256.0f;
    float x = (((float)w - cx) * d) / fx;
    float y = (((float)h - cy) * d) / fx;
    // np.round = RNE -> rintf; op order matches numpy rounding exactly.
    float tx = rintf(((x + 2.0f) * 0.25f) * 63.0f);
    float ty = rintf(((y + 2.0f) * 0.25f) * 63.0f);
    float tz = rintf(((d + 2.0f) * 0.25f) * 63.0f);
    ix = (int)tx; iy = (int)ty; iz = (int)tz;
    return !(ix < 0 || ix >= V || iy < 0 || iy >= V ||
             iz < 0 || iz >= V);
}

// ---- P0: cursor[kk4] = kk4*CAPQ; done[32] = 0 (right after cursors) ----
__global__ void dtv_init(unsigned* __restrict__ cursor) {
    int i = blockIdx.x * blockDim.x + threadIdx.x;
    if (i < NBUCKET)              cursor[i] = (unsigned)i * CAPQ;
    else if (i < NBUCKET + 32)    cursor[i] = 0;            // done[]
}

// ---- P1: fused persistent append(4 rounds) + reduce(8 rounds) ----
__global__ void __launch_bounds__(256, 4)
dtv_fused(const float* __restrict__ rgbd,
          unsigned* __restrict__ cursor,
          unsigned long long* __restrict__ entries,
          float* __restrict__ out) {
    int bid = blockIdx.x, t = threadIdx.x;
    unsigned* done = cursor + NBUCKET;

    __shared__ union {
        struct {
            unsigned lcnt[256], lpre[256], labs[256], wtot[4];
            unsigned long long stage[PPB];              // 16KB
        } a;                                            // ~19.1KB
        struct {
            unsigned long long A[1024], B[1024];        // 16KB
        } r;
    } sm;

    // ================= append phase =================
    for (int v = bid; v < 32 * CHUNKS; v += GRID) {
        int b = v >> 7, chunk = v & (CHUNKS - 1);

        sm.a.lcnt[t] = 0;
        __syncthreads();

        const float* bb = rgbd + (size_t)b * 4 * NPIX;
        const f4* r4 = (const f4*)(bb) + chunk * (PPB / 4);
        const f4* g4 = (const f4*)(bb + (size_t)NPIX) + chunk * (PPB / 4);
        const f4* b4 = (const f4*)(bb + (size_t)2 * NPIX) + chunk * (PPB / 4);
        const f4* d4 = (const f4*)(bb + (size_t)3 * NPIX) + chunk * (PPB / 4);
        int pbase = chunk * PPB;

        // Depth first (8 px/thread); rgb deferred to Pass B.
        f4 dv[2];
#pragma unroll
        for (int i = 0; i < 2; ++i)
            dv[i] = __builtin_nontemporal_load(&d4[t + i * 256]);

        unsigned meta[8];   // (bin<<24)|(iy<<18)|(iz<<12)|off(12)
#pragma unroll
        for (int i = 0; i < 2; ++i) {
            int p0 = pbase + 4 * (t + i * 256);
#pragma unroll
            for (int j = 0; j < 4; ++j) {
                float d = dv[i][j];
                int pix = p0 + j;
                int h = pix >> 9, w = pix & (Wd - 1);
                int ix, iy, iz;
                if (unproject(w, h, d, ix, iy, iz)) {
                    unsigned bin = ((unsigned)ix << 2) | ((unsigned)iy >> 4);
                    unsigned off = atomicAdd(&sm.a.lcnt[bin], 1u);
                    meta[i * 4 + j] = (bin << 24) | ((unsigned)iy << 18) |
                                      ((unsigned)iz << 12) | off;
                } else {
                    meta[i * 4 + j] = 0xFFFFFFFFu;
                }
            }
        }
        __syncthreads();

        // Hierarchical scan over 256 bins (4 waves) + global bump-alloc.
        {
            int wv = t >> 6, lane = t & 63;
            unsigned c = sm.a.lcnt[t];
            unsigned s = c;
#pragma unroll
            for (int off = 1; off < 64; off <<= 1) {
                unsigned vv = __shfl_up(s, off, 64);
                if (lane >= off) s += vv;
            }
            if (lane == 63) sm.a.wtot[wv] = s;
            __syncthreads();
            unsigned woff = 0;
#pragma unroll
            for (int k = 0; k < 3; ++k)
                if (k < wv) woff += sm.a.wtot[k];
            sm.a.lpre[t] = woff + s - c;
            sm.a.labs[t] = c ? atomicAdd(&cursor[b * 256 + t], c) : 0u;
        }
        __syncthreads();

        // Pass B: rgb loads overlap pack+stage.
        f4 rv[2], gv[2], bv[2];
#pragma unroll
        for (int i = 0; i < 2; ++i) {
            rv[i] = __builtin_nontemporal_load(&r4[t + i * 256]);
            gv[i] = __builtin_nontemporal_load(&g4[t + i * 256]);
            bv[i] = __builtin_nontemporal_load(&b4[t + i * 256]);
        }
#pragma unroll
        for (int i = 0; i < 2; ++i) {
#pragma unroll
            for (int j = 0; j < 4; ++j) {
                unsigned m = meta[i * 4 + j];
                if (m == 0xFFFFFFFFu) continue;
                unsigned bin = m >> 24, iy = (m >> 18) & 63u,
                         iz = (m >> 12) & 63u;
                unsigned ix = bin >> 2;
                unsigned off = m & 0xFFFu;
                unsigned long long r14 =
                    (unsigned long long)(unsigned)rintf(rv[i][j] * CQ);
                unsigned long long g14 =
                    (unsigned long long)(unsigned)rintf(gv[i][j] * CQ);
                unsigned long long b14 =
                    (unsigned long long)(unsigned)rintf(bv[i][j] * CQ);
                unsigned slot = sm.a.lpre[bin] + off;
                sm.a.stage[slot] = ((unsigned long long)ix << 57) |
                                   ((unsigned long long)iy << 51) |
                                   ((unsigned long long)iz << 45) |
                                   (r14 << 30) | (g14 << 15) | b14;
            }
        }
        __syncthreads();

        // Flush bin-sorted segments.
        unsigned total = sm.a.lpre[255] + sm.a.lcnt[255];
        for (unsigned e = t; e < total; e += 256) {
            unsigned long long ent = sm.a.stage[e];
            unsigned bin = (unsigned)(ent >> 55) & 255u;
            unsigned pos = sm.a.labs[bin] + (e - sm.a.lpre[bin]);
            unsigned kk4 = (unsigned)(b * 256) + bin;
            if (pos < (kk4 + 1) * CAPQ)           // capacity guard
                entries[(size_t)pos] = ent;
        }
        __threadfence();                          // push stores device-wide
        __syncthreads();                          // all threads fenced
        if (t == 0)
            __hip_atomic_fetch_add(&done[b], 1u, __ATOMIC_RELEASE,
                                   __HIP_MEMORY_SCOPE_AGENT);
    }

    // ================= reduce phase =================
    for (int u = bid; u < NBUCKET; u += GRID) {
        int b = u >> 8;
        // rotate (ix,quad) assignment per batch so each persistent block's
        // 8 buckets span the ix-heat spectrum (load balance).
        unsigned rest = ((unsigned)u + (unsigned)(u >> 8) * 37u) & 255u;
        unsigned rr = rest >> 2, quad = rest & 3u;
        int ix = (rr & 1u) ? (31 - (int)(rr >> 1)) : (32 + (int)(rr >> 1));
        int kk4 = b * 256 + ix * 4 + (int)quad;

        // Wait until all 128 append blocks of batch b have released.
        if (t == 0) {
            unsigned spins = 0;
            while (__hip_atomic_load(&done[b], __ATOMIC_ACQUIRE,
                                     __HIP_MEMORY_SCOPE_AGENT) < 128u) {
                __builtin_amdgcn_s_sleep(8);
                if (++spins > (1u << 26)) break;  // visible-fail escape
            }
        }
        __syncthreads();

        unsigned basew = (unsigned)kk4 * CAPQ;
        unsigned cnt = __hip_atomic_load(&cursor[kk4], __ATOMIC_RELAXED,
                                         __HIP_MEMORY_SCOPE_AGENT) - basew;
        if (cnt > CAPQ) cnt = CAPQ;
        unsigned npair = cnt >> 1;
        const ulonglong2* entries2 = (const ulonglong2*)entries;
        size_t base2 = (size_t)kk4 * (CAPQ / 2);

        ulonglong2 e2;
        if (t < (int)npair) e2 = entries2[base2 + t];

        ulonglong2* zA = (ulonglong2*)sm.r.A;
        ulonglong2* zB = (ulonglong2*)sm.r.B;
#pragma unroll
        for (int i = 0; i < 2; ++i) {
            zA[t + i * 256] = ulonglong2{0ULL, 0ULL};
            zB[t + i * 256] = ulonglong2{0ULL, 0ULL};
        }
        __syncthreads();

        auto accum = [&](unsigned long long p) {
            unsigned iy4 = (unsigned)(p >> 51) & 15u;
            unsigned iz  = (unsigned)(p >> 45) & 63u;
            unsigned vv = iy4 * 64u + iz;
            atomicAdd(&sm.r.A[vv], (1ULL << 32) | ((p >> 30) & 0x7FFFULL));
            atomicAdd(&sm.r.B[vv],
                      (((p >> 15) & 0x7FFFULL) << 32) | (p & 0x7FFFULL));
        };

        for (unsigned j = t; j < npair; j += 256) {
            ulonglong2 cur = e2;
            unsigned jn = j + 256;
            if (jn < npair) e2 = entries2[base2 + jn];
            accum(cur.x);
            accum(cur.y);
        }
        if ((cnt & 1u) && t == 0)
            accum(entries[(size_t)basew + cnt - 1]);
        __syncthreads();

        float* p0 = out + (size_t)b * 4 * V3 + (size_t)ix * 4096 + quad * 1024;
        int v0 = t * 4;
        f4 o0, o1, o2, o3;
#pragma unroll
        for (int j = 0; j < 4; ++j) {
            unsigned long long A = sm.r.A[v0 + j], Bw = sm.r.B[v0 + j];
            unsigned c = (unsigned)(A >> 32);
            float occ = 0.0f, r = 0.0f, g = 0.0f, bl = 0.0f;
            if (c) {
                float inv = 1.0f / (CQ * (float)c);
                occ = 1.0f;
                r  = (float)(unsigned)(A  & 0xFFFFFFFFULL) * inv;
                g  = (float)(unsigned)(Bw >> 32)            * inv;
                bl = (float)(unsigned)(Bw & 0xFFFFFFFFULL)  * inv;
            }
            o0[j] = occ; o1[j] = r; o2[j] = g; o3[j] = bl;
        }
        __builtin_nontemporal_store(o0, (f4*)(p0) + t);
        __builtin_nontemporal_store(o1, (f4*)(p0 + (size_t)V3) + t);
        __builtin_nontemporal_store(o2, (f4*)(p0 + (size_t)2 * V3) + t);
        __builtin_nontemporal_store(o3, (f4*)(p0 + (size_t)3 * V3) + t);
        __syncthreads();                          // LDS reuse next unit
    }
}

// ---------- fallback (generic B / tiny ws): proven R1 path ----------
__global__ void dtv_scatter_f32(const float* __restrict__ rgbd,
                                float* __restrict__ acc) {
    int idx = blockIdx.x * blockDim.x + threadIdx.x;
    int b   = idx >> 18;
    int pix = idx & (NPIX - 1);
    int h   = pix >> 9;
    int w   = pix & (Wd - 1);
    const float* base = rgbd + (size_t)b * 4 * NPIX;
    float d = base[(size_t)3 * NPIX + pix];
    int ix, iy, iz;
    if (!unproject(w, h, d, ix, iy, iz)) return;
    float r  = base[pix];
    float g  = base[(size_t)NPIX + pix];
    float bl = base[(size_t)2 * NPIX + pix];
    float* ob = acc + (size_t)b * 4 * V3;
    int vlin = (ix * V + iy) * V + iz;
    atomicAdd(ob + vlin, 1.0f);
    atomicAdd(ob + (size_t)V3 + vlin, r);
    atomicAdd(ob + (size_t)2 * V3 + vlin, g);
    atomicAdd(ob + (size_t)3 * V3 + vlin, bl);
}

__global__ void dtv_finalize_f32(float* __restrict__ out) {
    int idx = blockIdx.x * blockDim.x + threadIdx.x;
    int b    = idx >> 18;
    int vlin = idx & (V3 - 1);
    float* p = out + (size_t)b * 4 * V3;
    float c  = p[vlin];
    float r  = p[(size_t)V3 + vlin];
    float g  = p[(size_t)2 * V3 + vlin];
    float bl = p[(size_t)3 * V3 + vlin];
    bool occ = (c > 0.0f);
    p[vlin]                  = occ ? 1.0f : 0.0f;
    p[(size_t)V3 + vlin]     = occ ? (r / c)  : 0.0f;
    p[(size_t)2 * V3 + vlin] = occ ? (g / c)  : 0.0f;
    p[(size_t)3 * V3 + vlin] = occ ? (bl / c) : 0.0f;
}

extern "C" void kernel_launch(void* const* d_in, const int* in_sizes, int n_in,
                              void* d_out, int out_size, void* d_ws, size_t ws_size,
                              hipStream_t stream) {
    const float* rgbd = (const float*)d_in[0];
    float* out = (float*)d_out;
    const int B = in_sizes[0] / (4 * NPIX);   // 32

    // ws: [0,32K) cursor[8192] | [32K,32K+128) done[32] | [64K,...) entries
    size_t need = 65536 + (size_t)NBUCKET * CAPQ * sizeof(unsigned long long);

    if (B == 32 && ws_size >= need) {
        unsigned* cursor = (unsigned*)d_ws;
        unsigned long long* entries =
            (unsigned long long*)((char*)d_ws + 65536);
        dtv_init <<<(NBUCKET + 32 + 255) / 256, 256, 0, stream>>>(cursor);
        dtv_fused<<<GRID, 256, 0, stream>>>(rgbd, cursor, entries, out);
    } else {
        (void)hipMemsetAsync(d_out, 0, (size_t)out_size * sizeof(float), stream);
        int total_pix = B * NPIX;
        int total_vox = B * V3;
        dtv_scatter_f32 <<<(total_pix + 255) / 256, 256, 0, stream>>>(rgbd, out);
        dtv_finalize_f32<<<(total_vox + 255) / 256, 256, 0, stream>>>(out);
    }
}

// Round 9
// 240.052 us; speedup vs baseline: 4.3121x; 4.3121x over previous
//
#include <hip/hip_runtime.h>
#include <math.h>

// DepthToVoxelConverter: B=32, (B,4,512,512) fp32 -> (B,4,64^3) fp32
// out ch0 = occupancy, ch1..3 = mean rgb per voxel.
//
// History:
//  R1-R8: scatter-atomics -> bucket+LDS-reduce evolution, 430->242us.
//  R9: entry repack (ix in u64, Q14, bkt[] deleted), hot-first reduce
//      dispatch, nontemporal ld/st: 242.2us (best).
//  R10: CAP 30000->7680 (entries 491->120MB): 242.5 (tied). ws poison is
//      a FIXED 512MiB tax; fixed harness overhead ~150-158us/iter.
//  R11: quad-segregated fine buckets: NULL (242.7).
//  R12: rgb GATHER in reduce: 303.5 REGRESSION (reduce=121us measured:
//      latency-bound cross-XCD gather). Colors must stream through append.
//  R13: 512thr append, depth-only across barriers: 244.8 (null).
//  R14: MEASUREMENT: in-dispatch doubled append => append ~31-35us
//      (floor ~24); reduce ~30 (floor ~26, from R12). Slack ~15us total.
//  R15: fused persistent kernel + device-scope flags: 1035us CATASTROPHE.
//      Per-round device fences (L2 writeback class) + persistent grid
//      killing inter-block load pipelining. Launch boundaries are CHEAP
//      on this chip relative to software cross-kernel sync.
//  R16: revert to R10 form (= R9 structure, CAP 7680). PLATEAU:
//      controllable ~92us vs ~50us floor; remaining slack is
//      latency/barrier-shaped; all named levers tested and null.
//
// Entry u64 layout (both LDS staging and global):
//   [62:57]=ix [56:51]=iy [50:45]=iz [44:30]=r14 [29:15]=g14 [14:0]=b14

constexpr int V = 64;
constexpr int V3 = V * V * V;           // 262144 = 2^18
constexpr int Wd = 512, Hd = 512;
constexpr int NPIX = Wd * Hd;           // 262144 = 2^18
constexpr int NBUCKET = 32 * 64;        // (b, ix) coarse buckets
constexpr unsigned CAP = 7680;          // entries per bucket (8B each, even)
constexpr float CQ = 16384.0f;          // color quant Q14
constexpr int PPB = 2048;               // pixels per append block
constexpr int CHUNKS = NPIX / PPB;      // 128 chunks per batch

// clang-native 4-float vector: required by __builtin_nontemporal_{load,store}
// (HIP's float4 is a class type the builtin rejects). Same 16B layout.
typedef float f4 __attribute__((ext_vector_type(4)));

__device__ __forceinline__ bool unproject(int w, int h, float d,
                                          int& ix, int& iy, int& iz) {
    // depth_valid = (d > 0) & (d < 10) & isfinite(d)
    if (!(d > 0.0f) || !(d < 10.0f) || !isfinite(d)) return false;
    const float fx = 256.0f, cx = 256.0f, cy = 256.0f;
    float x = (((float)w - cx) * d) / fx;
    float y = (((float)h - cy) * d) / fx;
    // np.round = RNE -> rintf; op order matches numpy rounding exactly.
    float tx = rintf(((x + 2.0f) * 0.25f) * 63.0f);
    float ty = rintf(((y + 2.0f) * 0.25f) * 63.0f);
    float tz = rintf(((d + 2.0f) * 0.25f) * 63.0f);
    ix = (int)tx; iy = (int)ty; iz = (int)tz;
    return !(ix < 0 || ix >= V || iy < 0 || iy >= V ||
             iz < 0 || iz >= V);
}

// ---- P0: cursor[kk] = kk*CAP (bump-allocator bases) ----
__global__ void dtv_cursor_init(unsigned* __restrict__ cursor) {
    int i = blockIdx.x * blockDim.x + threadIdx.x;   // 0..2047
    cursor[i] = (unsigned)i * CAP;
}

// ---- P1: append, LDS-staged + bucket-sorted flush, rgb prefetch ----
// 4096 blocks x 256 thr; block = (b, chunk of 2048 pixels).
__global__ void __launch_bounds__(256)
dtv_append4(const float* __restrict__ rgbd,
            unsigned* __restrict__ cursor,
            unsigned long long* __restrict__ entries) {
    int blk = blockIdx.x;
    int b = blk >> 7, chunk = blk & (CHUNKS - 1), t = threadIdx.x;

    __shared__ unsigned lcnt[64];
    __shared__ unsigned lpre[64];    // block-local exclusive prefix
    __shared__ unsigned labs[64];    // global bucket base for this block
    __shared__ unsigned long long stage[PPB];   // bucket-sorted entries

    if (t < 64) lcnt[t] = 0;
    __syncthreads();

    const float* bb = rgbd + (size_t)b * 4 * NPIX;
    const f4* r4 = (const f4*)(bb) + chunk * (PPB / 4);
    const f4* g4 = (const f4*)(bb + (size_t)NPIX) + chunk * (PPB / 4);
    const f4* b4 = (const f4*)(bb + (size_t)2 * NPIX) + chunk * (PPB / 4);
    const f4* d4 = (const f4*)(bb + (size_t)3 * NPIX) + chunk * (PPB / 4);
    int pbase = chunk * PPB;

    // Prefetch ALL planes into registers up front (nontemporal: pure
    // stream, no reuse): loads in flight during key computation, LDS
    // atomics, barrier, and scan.
    f4 dv[2], rv[2], gv[2], bv[2];
#pragma unroll
    for (int i = 0; i < 2; ++i) dv[i] = __builtin_nontemporal_load(&d4[t + i * 256]);
#pragma unroll
    for (int i = 0; i < 2; ++i) {
        rv[i] = __builtin_nontemporal_load(&r4[t + i * 256]);
        gv[i] = __builtin_nontemporal_load(&g4[t + i * 256]);
        bv[i] = __builtin_nontemporal_load(&b4[t + i * 256]);
    }

    // Pass A: depth -> keys + block-local offsets.
    unsigned meta[8];   // (ix<<24)|(iy<<18)|(iz<<12)|off(12) ; ~0u invalid
#pragma unroll
    for (int i = 0; i < 2; ++i) {
        int p0 = pbase + 4 * (t + i * 256);
#pragma unroll
        for (int j = 0; j < 4; ++j) {
            float d = dv[i][j];
            int pix = p0 + j;
            int h = pix >> 9, w = pix & (Wd - 1);
            int ix, iy, iz;
            if (unproject(w, h, d, ix, iy, iz)) {
                unsigned off = atomicAdd(&lcnt[ix], 1u);
                meta[i * 4 + j] = ((unsigned)ix << 24) | ((unsigned)iy << 18) |
                                  ((unsigned)iz << 12) | off;
            } else {
                meta[i * 4 + j] = 0xFFFFFFFFu;
            }
        }
    }
    __syncthreads();

    // Wave 0: 64-lane inclusive shfl-scan over bins; global bump-alloc.
    if (t < 64) {
        unsigned c = lcnt[t];
        unsigned s = c;
#pragma unroll
        for (int off = 1; off < 64; off <<= 1) {
            unsigned v = __shfl_up(s, off, 64);
            if (t >= off) s += v;
        }
        lpre[t] = s - c;
        labs[t] = c ? atomicAdd(&cursor[b * 64 + t], c) : 0u;
    }
    __syncthreads();

    // Pass B: pack from registers, write bucket-sorted into LDS staging.
    // ix travels inside the entry -> no side array needed.
#pragma unroll
    for (int i = 0; i < 2; ++i) {
#pragma unroll
        for (int j = 0; j < 4; ++j) {
            unsigned m = meta[i * 4 + j];
            if (m == 0xFFFFFFFFu) continue;
            unsigned ix = m >> 24, iy = (m >> 18) & 63u, iz = (m >> 12) & 63u;
            unsigned off = m & 0xFFFu;
            float r  = rv[i][j];
            float g  = gv[i][j];
            float bl = bv[i][j];
            unsigned long long r14 = (unsigned long long)(unsigned)rintf(r  * CQ);
            unsigned long long g14 = (unsigned long long)(unsigned)rintf(g  * CQ);
            unsigned long long b14 = (unsigned long long)(unsigned)rintf(bl * CQ);
            unsigned slot = lpre[ix] + off;
            stage[slot] = ((unsigned long long)ix << 57) |
                          ((unsigned long long)iy << 51) |
                          ((unsigned long long)iz << 45) |
                          (r14 << 30) | (g14 << 15) | b14;
        }
    }
    __syncthreads();

    // Flush: consecutive threads -> consecutive addresses per bucket segment.
    unsigned total = lpre[63] + lcnt[63];
    for (unsigned e = t; e < total; e += 256) {
        unsigned long long ent = stage[e];
        unsigned ix = (unsigned)(ent >> 57) & 63u;
        unsigned pos = labs[ix] + (e - lpre[ix]);
        unsigned kk = (unsigned)(b * 64) + ix;
        if (pos < (kk + 1) * CAP)                 // capacity guard
            entries[(size_t)pos] = ent;
    }
}

// ---- P2: 4 blocks per (b,ix) coarse bucket, each owns iy-quadrant ----
// 8192 blocks x 256 thr, 16KiB LDS -> 8 blocks/CU resident.
// Hot-first dispatch: ix rank center-out (32,31,33,30,...) lives in the
// HIGH bits of blockIdx so the heaviest buckets launch first and the
// lightest form the tail (straggler removal).
__global__ void __launch_bounds__(256)
dtv_reduce4(const ulonglong2* __restrict__ entries2,
            const unsigned* __restrict__ cursor,
            float* __restrict__ out) {
    int bq = blockIdx.x;                        // 0..8191
    unsigned rank = (unsigned)bq >> 7;          // 0..63, hottest first
    int ix = (rank & 1u) ? (31 - (int)(rank >> 1)) : (32 + (int)(rank >> 1));
    int b  = (bq >> 2) & 31;
    unsigned quad = (unsigned)(bq & 3);
    int kk = b * 64 + ix;
    int t = threadIdx.x;

    __shared__ unsigned long long ldsA[1024];  // (count<<32)|rsum
    __shared__ unsigned long long ldsB[1024];  // (gsum <<32)|bsum

    unsigned basew = (unsigned)kk * CAP;            // u64 units
    unsigned cnt = cursor[kk] - basew;
    if (cnt > CAP) cnt = CAP;
    unsigned npair = cnt >> 1;
    size_t base2 = (size_t)kk * (CAP / 2);          // vec2 units

    // Prefetch first iteration's pair while zeroing LDS.
    ulonglong2 e2;
    if (t < (int)npair) e2 = entries2[base2 + t];

    ulonglong2* zA = (ulonglong2*)ldsA;             // 512 vec2
    ulonglong2* zB = (ulonglong2*)ldsB;
#pragma unroll
    for (int i = 0; i < 2; ++i) {
        zA[t + i * 256] = ulonglong2{0ULL, 0ULL};
        zB[t + i * 256] = ulonglong2{0ULL, 0ULL};
    }
    __syncthreads();

    auto accum = [&](unsigned long long p) {
        if (((unsigned)(p >> 55) & 3u) != quad) return;   // iy>>4 filter
        unsigned iy4 = (unsigned)(p >> 51) & 15u;         // iy & 15
        unsigned iz  = (unsigned)(p >> 45) & 63u;
        unsigned v = iy4 * 64u + iz;
        atomicAdd(&ldsA[v], (1ULL << 32) | ((p >> 30) & 0x7FFFULL));
        atomicAdd(&ldsB[v], (((p >> 15) & 0x7FFFULL) << 32) | (p & 0x7FFFULL));
    };

    for (unsigned j = t; j < npair; j += 256) {
        ulonglong2 cur = e2;
        unsigned jn = j + 256;
        if (jn < npair) e2 = entries2[base2 + jn];  // prefetch next
        accum(cur.x);
        accum(cur.y);
    }
    if ((cnt & 1u) && t == 0) {
        const unsigned long long* e1 = (const unsigned long long*)entries2;
        accum(e1[(size_t)basew + cnt - 1]);
    }
    __syncthreads();

    float* p0 = out + (size_t)b * 4 * V3 + (size_t)ix * 4096 + quad * 1024;
    int v0 = t * 4;                                 // 4 consecutive voxels
    f4 o0, o1, o2, o3;
#pragma unroll
    for (int j = 0; j < 4; ++j) {
        unsigned long long A = ldsA[v0 + j], Bw = ldsB[v0 + j];
        unsigned c = (unsigned)(A >> 32);
        float occ = 0.0f, r = 0.0f, g = 0.0f, bl = 0.0f;
        if (c) {
            float inv = 1.0f / (CQ * (float)c);
            occ = 1.0f;
            r  = (float)(unsigned)(A  & 0xFFFFFFFFULL) * inv;
            g  = (float)(unsigned)(Bw >> 32)            * inv;
            bl = (float)(unsigned)(Bw & 0xFFFFFFFFULL)  * inv;
        }
        o0[j] = occ; o1[j] = r; o2[j] = g; o3[j] = bl;
    }
    // Output is a pure write-once stream: nontemporal, keep L2 for entries.
    __builtin_nontemporal_store(o0, (f4*)(p0) + t);
    __builtin_nontemporal_store(o1, (f4*)(p0 + (size_t)V3) + t);
    __builtin_nontemporal_store(o2, (f4*)(p0 + (size_t)2 * V3) + t);
    __builtin_nontemporal_store(o3, (f4*)(p0 + (size_t)3 * V3) + t);
}

// ---------- fallback (generic B / tiny ws): proven R1 path ----------
__global__ void dtv_scatter_f32(const float* __restrict__ rgbd,
                                float* __restrict__ acc) {
    int idx = blockIdx.x * blockDim.x + threadIdx.x;
    int b   = idx >> 18;
    int pix = idx & (NPIX - 1);
    int h   = pix >> 9;
    int w   = pix & (Wd - 1);
    const float* base = rgbd + (size_t)b * 4 * NPIX;
    float d = base[(size_t)3 * NPIX + pix];
    int ix, iy, iz;
    if (!unproject(w, h, d, ix, iy, iz)) return;
    float r  = base[pix];
    float g  = base[(size_t)NPIX + pix];
    float bl = base[(size_t)2 * NPIX + pix];
    float* ob = acc + (size_t)b * 4 * V3;
    int vlin = (ix * V + iy) * V + iz;
    atomicAdd(ob + vlin, 1.0f);
    atomicAdd(ob + (size_t)V3 + vlin, r);
    atomicAdd(ob + (size_t)2 * V3 + vlin, g);
    atomicAdd(ob + (size_t)3 * V3 + vlin, bl);
}

__global__ void dtv_finalize_f32(float* __restrict__ out) {
    int idx = blockIdx.x * blockDim.x + threadIdx.x;
    int b    = idx >> 18;
    int vlin = idx & (V3 - 1);
    float* p = out + (size_t)b * 4 * V3;
    float c  = p[vlin];
    float r  = p[(size_t)V3 + vlin];
    float g  = p[(size_t)2 * V3 + vlin];
    float bl = p[(size_t)3 * V3 + vlin];
    bool occ = (c > 0.0f);
    p[vlin]                  = occ ? 1.0f : 0.0f;
    p[(size_t)V3 + vlin]     = occ ? (r / c)  : 0.0f;
    p[(size_t)2 * V3 + vlin] = occ ? (g / c)  : 0.0f;
    p[(size_t)3 * V3 + vlin] = occ ? (bl / c) : 0.0f;
}

extern "C" void kernel_launch(void* const* d_in, const int* in_sizes, int n_in,
                              void* d_out, int out_size, void* d_ws, size_t ws_size,
                              hipStream_t stream) {
    const float* rgbd = (const float*)d_in[0];
    float* out = (float*)d_out;
    const int B = in_sizes[0] / (4 * NPIX);   // 32

    // ws layout: [0, 8K) cursor | [8K, 8K + NBUCKET*CAP*8) entries (~120MB)
    size_t need = 8192 + (size_t)NBUCKET * CAP * sizeof(unsigned long long);

    if (B == 32 && ws_size >= need) {
        unsigned* cursor = (unsigned*)d_ws;
        unsigned long long* entries =
            (unsigned long long*)((char*)d_ws + 8192);
        dtv_cursor_init<<<NBUCKET / 256, 256, 0, stream>>>(cursor);
        dtv_append4    <<<B * CHUNKS, 256, 0, stream>>>(rgbd, cursor, entries);
        dtv_reduce4    <<<NBUCKET * 4, 256, 0, stream>>>((const ulonglong2*)entries,
                                                         cursor, out);
    } else {
        (void)hipMemsetAsync(d_out, 0, (size_t)out_size * sizeof(float), stream);
        int total_pix = B * NPIX;
        int total_vox = B * V3;
        dtv_scatter_f32 <<<(total_pix + 255) / 256, 256, 0, stream>>>(rgbd, out);
        dtv_finalize_f32<<<(total_vox + 255) / 256, 256, 0, stream>>>(out);
    }
}